// Round 1
// 172.005 us; speedup vs baseline: 1.0598x; 1.0598x over previous
//
#include <hip/hip_runtime.h>
#include <math.h>

// DecoderLayer: B=4,N=1,S=256,D=128,H=128,DFF=512, fp32 end-to-end.
// Round-10: same 5-dispatch structure as R9 (structural: 5 serial stages).
// Change: ALL blocks go 256 -> 512 threads (1 -> 2 waves/SIMD) with
// reduction-dim splitting + LDS partial exchange. Theory: R9 ran every stage
// at 1 wave/SIMD (256 blocks x 256 thr = 4 waves/CU) -> every dep-chain /
// LDS / L2 latency fully exposed (measured ~85K cyc/block vs ~8K issue-bound).
//  - proj3: mm #1 k-split x2; {qa,kb} computed concurrently (thread doubling)
//  - pairwise: h-split x2, 1 extra barrier + partial exchange
//  - attn_tail: AV/outproj/q2w k-split x4, qa2/qb2 k-split x2, ffn1 k-split x4,
//    ffn2 16 k-groups
// Grid law (R6/R7): never below 256 blocks. R3: grid.sync ~40us -> no coop.
// b2 dropped (softmax shift invariance). RES_RATIO=1 -> plain residual add.

#define LN_EPS 1e-6f
#define NEGV  (-1e9f)

constexpr int B = 4, S = 256, D = 128, H = 128, DFF = 512;
constexpr int R = B * S;   // 1024 rows (N=1)
constexpr int LDW = H + 4; // padded pairwise LDS stride (16B-aligned rows)

struct P {
    const float *x, *enc, *com_mask, *dec_mask;
    const float *W1q, *W1k, *b1, *W2;
    const float *Ww1, *bw1, *Wd1, *bd1;
    const float *Ww2, *bw2, *Wd2, *bd2;
    const float *Wf1, *bf1, *Wf2, *bf2;
    const float *ln1g, *ln1b, *ln2g, *ln2b, *ln3g, *ln3b;
    float *out;
    float *xw, *qa, *kb, *kv2w, *kb2, *ka2, *qa2, *qb2;
    float *sbuf, *sbuf2, *out1;
};

// ================= 1: chained projections, grid (R/8, 2), 512 thr =========
__global__ __launch_bounds__(512) void proj3_kernel(P p)
{
    const int g = blockIdx.y, tid = threadIdx.x;
    const int r0 = blockIdx.x * 8;
    __shared__ __align__(16) float Ash[8 * 128];
    __shared__ __align__(16) float Pw[8 * 128];
    __shared__ __align__(16) float Pp[2 * 8 * 128];  // k-split partials

    const float* A    = g ? p.enc  : p.x;
    const float* Wp   = g ? p.Ww2  : p.Ww1;
    const float* bp   = g ? p.bw2  : p.bw1;
    float*       o_w  = g ? p.kv2w : p.xw;
    const float* Wsec = g ? p.W1k  : p.W1q;  // kb2 | qa
    const float* bsec = g ? nullptr: p.b1;
    float*       o_s  = g ? p.kb2  : p.qa;
    const float* Wthr = g ? p.W1q  : p.W1k;  // ka2 | kb
    float*       o_t  = g ? p.ka2  : p.kb;

    if (tid < 256)
        ((float4*)Ash)[tid] = ((const float4*)(A + (size_t)r0 * 128))[tid];
    __syncthreads();

    // ---- xw = A@Wp + bp, k-split x2 (64-deep chains) ----
    {
        const int kh = tid >> 8, unit = tid & 255, lr = unit >> 5, c4 = unit & 31;
        const float4* W4 = (const float4*)Wp;
        float4 acc = (kh == 0) ? ((const float4*)bp)[c4] : make_float4(0.f, 0.f, 0.f, 0.f);
        const int k0 = kh * 64;
        #pragma unroll 8
        for (int k = 0; k < 64; ++k) {
            const float a = Ash[lr * 128 + k0 + k];
            const float4 w = W4[(k0 + k) * 32 + c4];
            acc.x = fmaf(a, w.x, acc.x); acc.y = fmaf(a, w.y, acc.y);
            acc.z = fmaf(a, w.z, acc.z); acc.w = fmaf(a, w.w, acc.w);
        }
        ((float4*)Pp)[kh * 256 + unit] = acc;
    }
    __syncthreads();
    if (tid < 256) {
        const int lr = tid >> 5, c4 = tid & 31;
        const float4 a = ((const float4*)Pp)[tid];
        const float4 bq = ((const float4*)Pp)[256 + tid];
        const float4 w = make_float4(a.x + bq.x, a.y + bq.y, a.z + bq.z, a.w + bq.w);
        ((float4*)Pw)[tid] = w;
        ((float4*)o_w)[(size_t)(r0 + lr) * 32 + c4] = w;
    }
    __syncthreads();

    // ---- {qa,kb} (or {kb2,ka2}) concurrently: which = tid>>8 ----
    {
        const int which = tid >> 8, unit = tid & 255, lr = unit >> 5, c4 = unit & 31;
        const float* W = which ? Wthr : Wsec;
        const float* bb = which ? nullptr : bsec;
        float* o = which ? o_t : o_s;
        const float4* W4 = (const float4*)W;
        float4 acc = bb ? ((const float4*)bb)[c4] : make_float4(0.f, 0.f, 0.f, 0.f);
        #pragma unroll 8
        for (int k = 0; k < 128; ++k) {
            const float a = Pw[lr * 128 + k];
            const float4 w = W4[k * 32 + c4];
            acc.x = fmaf(a, w.x, acc.x); acc.y = fmaf(a, w.y, acc.y);
            acc.z = fmaf(a, w.z, acc.z); acc.w = fmaf(a, w.w, acc.w);
        }
        ((float4*)o)[(size_t)(r0 + lr) * 32 + c4] = acc;
    }
}

// ---- pairwise accumulate helper (float4 over h), parameterized accs ----
#define PW_STEP_N(AP0, AP1, BP0, BP1, A00, A01, A10, A11)                      \
    {                                                                          \
        const float4 w  = *(const float4*)(W2s + h);                           \
        const float4 a0 = *(const float4*)((AP0) + h);                         \
        const float4 a1 = *(const float4*)((AP1) + h);                         \
        const float4 b0 = *(const float4*)((BP0) + h);                         \
        const float4 b1 = *(const float4*)((BP1) + h);                         \
        A00 = fmaf(fmaxf(a0.x+b0.x,0.f),w.x,A00); A00 = fmaf(fmaxf(a0.y+b0.y,0.f),w.y,A00); \
        A00 = fmaf(fmaxf(a0.z+b0.z,0.f),w.z,A00); A00 = fmaf(fmaxf(a0.w+b0.w,0.f),w.w,A00); \
        A01 = fmaf(fmaxf(a0.x+b1.x,0.f),w.x,A01); A01 = fmaf(fmaxf(a0.y+b1.y,0.f),w.y,A01); \
        A01 = fmaf(fmaxf(a0.z+b1.z,0.f),w.z,A01); A01 = fmaf(fmaxf(a0.w+b1.w,0.f),w.w,A01); \
        A10 = fmaf(fmaxf(a1.x+b0.x,0.f),w.x,A10); A10 = fmaf(fmaxf(a1.y+b0.y,0.f),w.y,A10); \
        A10 = fmaf(fmaxf(a1.z+b0.z,0.f),w.z,A10); A10 = fmaf(fmaxf(a1.w+b0.w,0.f),w.w,A10); \
        A11 = fmaf(fmaxf(a1.x+b1.x,0.f),w.x,A11); A11 = fmaf(fmaxf(a1.y+b1.y,0.f),w.y,A11); \
        A11 = fmaf(fmaxf(a1.z+b1.z,0.f),w.z,A11); A11 = fmaf(fmaxf(a1.w+b1.w,0.f),w.w,A11); \
    }

// ================= 2: self pairwise (single term), 512 thr, h-split =======
__global__ __launch_bounds__(512) void pairwise_self_kernel(P p)
{
    __shared__ __align__(16) float As[32 * LDW];
    __shared__ __align__(16) float Bs[32 * LDW];
    __shared__ __align__(16) float W2s[H];
    __shared__ __align__(16) float Pp[256 * 4];
    const int b = blockIdx.z, q0 = blockIdx.y * 32, k0 = blockIdx.x * 32;
    const int tid = threadIdx.x, bS = b * S;
    for (int i = tid; i < 32 * (H / 4); i += 512) {
        const int r = i >> 5, c4 = i & 31;
        ((float4*)(As + r * LDW))[c4] = ((const float4*)(p.qa + (size_t)(bS + q0 + r) * H))[c4];
        ((float4*)(Bs + r * LDW))[c4] = ((const float4*)(p.kb + (size_t)(bS + k0 + r) * H))[c4];
    }
    if (tid < H / 4) ((float4*)W2s)[tid] = ((const float4*)p.W2)[tid];
    __syncthreads();
    const int hh = tid >> 8, unit = tid & 255;
    const int tx = unit & 15, ty = unit >> 4;
    const float* A0 = As + (2 * ty) * LDW; const float* A1 = A0 + LDW;
    const float* B0 = Bs + (2 * tx) * LDW; const float* B1 = B0 + LDW;
    float acc00 = 0.f, acc01 = 0.f, acc10 = 0.f, acc11 = 0.f;
    const int hbase = hh * 64;
    #pragma unroll 4
    for (int hi = 0; hi < 64; hi += 4) {
        const int h = hbase + hi;
        PW_STEP_N(A0, A1, B0, B1, acc00, acc01, acc10, acc11);
    }
    if (hh) ((float4*)Pp)[unit] = make_float4(acc00, acc01, acc10, acc11);
    __syncthreads();
    if (!hh) {
        const float4 o = ((const float4*)Pp)[unit];
        const size_t base = (size_t)(bS + q0 + 2 * ty) * S + (k0 + 2 * tx);
        *(float2*)(p.sbuf + base)     = make_float2(acc00 + o.x, acc01 + o.y);
        *(float2*)(p.sbuf + base + S) = make_float2(acc10 + o.z, acc11 + o.w);
    }
}

// ===== 4: cross pairwise, both symmetric terms, 512 thr, h-split ==========
__global__ __launch_bounds__(512) void pairwise_cross2_kernel(P p)
{
    __shared__ __align__(16) float As1[32 * LDW];
    __shared__ __align__(16) float Bs1[32 * LDW];
    __shared__ __align__(16) float As2[32 * LDW];
    __shared__ __align__(16) float Bs2[32 * LDW];
    __shared__ __align__(16) float W2s[H];
    __shared__ __align__(16) float Pp8[256 * 8];
    const int b = blockIdx.z, q0 = blockIdx.y * 32, k0 = blockIdx.x * 32;
    const int tid = threadIdx.x, bS = b * S;

    for (int i = tid; i < 32 * (H / 4); i += 512) {
        const int r = i >> 5, c4 = i & 31;
        ((float4*)(As1 + r * LDW))[c4] = ((const float4*)(p.qa2 + (size_t)(bS + q0 + r) * H))[c4];
        ((float4*)(Bs1 + r * LDW))[c4] = ((const float4*)(p.kb2 + (size_t)(bS + k0 + r) * H))[c4];
        ((float4*)(As2 + r * LDW))[c4] = ((const float4*)(p.qb2 + (size_t)(bS + q0 + r) * H))[c4];
        ((float4*)(Bs2 + r * LDW))[c4] = ((const float4*)(p.ka2 + (size_t)(bS + k0 + r) * H))[c4];
    }
    if (tid < H / 4) ((float4*)W2s)[tid] = ((const float4*)p.W2)[tid];
    __syncthreads();

    const int hh = tid >> 8, unit = tid & 255;
    const int tx = unit & 15, ty = unit >> 4;
    const float* A0 = As1 + (2 * ty) * LDW; const float* A1 = A0 + LDW;
    const float* B0 = Bs1 + (2 * tx) * LDW; const float* B1 = B0 + LDW;
    const float* C0 = As2 + (2 * ty) * LDW; const float* C1 = C0 + LDW;
    const float* D0 = Bs2 + (2 * tx) * LDW; const float* D1 = D0 + LDW;
    float a00 = 0.f, a01 = 0.f, a10 = 0.f, a11 = 0.f;
    float b00 = 0.f, b01 = 0.f, b10 = 0.f, b11 = 0.f;
    const int hbase = hh * 64;
    #pragma unroll 4
    for (int hi = 0; hi < 64; hi += 4) {
        const int h = hbase + hi;
        PW_STEP_N(A0, A1, B0, B1, a00, a01, a10, a11);
        PW_STEP_N(C0, C1, D0, D1, b00, b01, b10, b11);
    }
    if (hh) {
        ((float4*)Pp8)[unit * 2]     = make_float4(a00, a01, a10, a11);
        ((float4*)Pp8)[unit * 2 + 1] = make_float4(b00, b01, b10, b11);
    }
    __syncthreads();
    if (!hh) {
        const float4 o1 = ((const float4*)Pp8)[unit * 2];
        const float4 o2 = ((const float4*)Pp8)[unit * 2 + 1];
        const size_t base = (size_t)(bS + q0 + 2 * ty) * S + (k0 + 2 * tx);
        *(float2*)(p.sbuf2 + base)     = make_float2(a00 + b00 + o1.x + o2.x, a01 + b01 + o1.y + o2.y);
        *(float2*)(p.sbuf2 + base + S) = make_float2(a10 + b10 + o1.z + o2.z, a11 + b11 + o1.w + o2.w);
    }
}

// ======= 3/5: 4-row attn tail, 512 thr: softmax(+sym)+AV+outproj+res+LN ====
// grid = R/4 = 256 blocks. 8 waves/block = 2 waves/SIMD. All matmul phases
// k-split x4 (AV, outproj, q2w, ffn1) or x2 (qa2/qb2); partials through LDS.
// smem carve (floats), attn base: rowS [0,512) | s8 [512,1536) |
//   avp [1536,3584) | aoS [3584,4096) | pp [4096,6144)
// QPROJ aliases (post-LN, attn scratch dead): qpp=s8@512 (2048) |
//   q2wS @2560 (512) | qp2 @1536..3584 (2048, avp+aoS region)
// FFN aliases: hidP [512,8704) | part [8704,16896)
template<bool SYM, bool QPROJ, bool FFN>
__global__ __launch_bounds__(512) void attn_tail_kernel(P p)
{
    __shared__ __align__(16) float smem[FFN ? 16896 : 6144];
    float* rowS = smem;
    float* s8   = smem + 512;
    float* avp  = smem + 1536;
    float* aoS  = smem + 3584;
    float* pp   = smem + 4096;

    const float* Sin  = SYM ? p.sbuf : p.sbuf2;
    const float* mask = SYM ? p.com_mask : p.dec_mask;
    const float* V    = SYM ? p.xw : p.kv2w;
    const float* Wd   = SYM ? p.Wd1 : p.Wd2;
    const float* bd   = SYM ? p.bd1 : p.bd2;
    const float* res  = SYM ? p.x : p.out1;
    const float* lg   = SYM ? p.ln1g : p.ln2g;
    const float* lb   = SYM ? p.ln1b : p.ln2b;

    const int tid = threadIdx.x;
    const int r0 = blockIdx.x * 4, b = r0 >> 8, bS = b * S;

    // ---- scores + mask (+sym transpose) into s8[4][256] ----
    for (int i = tid; i < 4 * 256; i += 512) {
        const int r = i >> 8, k = i & 255;
        const int row = r0 + r, q = row & 255;
        float l = Sin[(size_t)row * S + k];
        if (SYM) l += Sin[(size_t)(bS + k) * S + q];
        l += mask[(size_t)row * S + k] * NEGV;
        s8[i] = l;
    }
    __syncthreads();

    // ---- softmax: waves 0-3 own rows 0-3; 64-lane shuffles ----
    {
        const int g = tid >> 6, c = tid & 63;
        if (g < 4) {
            float* rowp = s8 + g * 256;
            float m = -INFINITY;
            #pragma unroll
            for (int k = c; k < 256; k += 64) m = fmaxf(m, rowp[k]);
            for (int o = 32; o; o >>= 1) m = fmaxf(m, __shfl_xor(m, o, 64));
            float s = 0.f;
            #pragma unroll
            for (int k = c; k < 256; k += 64) { const float e = __expf(rowp[k] - m); rowp[k] = e; s += e; }
            for (int o = 32; o; o >>= 1) s += __shfl_xor(s, o, 64);
            const float rinv = 1.f / s;
            #pragma unroll
            for (int k = c; k < 256; k += 64) rowp[k] *= rinv;
        }
    }
    __syncthreads();

    // ---- AV, k-split x4: row r, quarter kq ----
    {
        const int r = tid >> 7, t = tid & 127, kq = t >> 5, c4 = t & 31;
        const float4* V4 = (const float4*)(V + (size_t)bS * D);
        const float* sp = s8 + r * 256 + kq * 64;
        float4 acc = make_float4(0.f, 0.f, 0.f, 0.f);
        #pragma unroll 8
        for (int k = 0; k < 64; ++k) {
            const float a = sp[k];
            const float4 v = V4[(kq * 64 + k) * 32 + c4];
            acc.x = fmaf(a, v.x, acc.x); acc.y = fmaf(a, v.y, acc.y);
            acc.z = fmaf(a, v.z, acc.z); acc.w = fmaf(a, v.w, acc.w);
        }
        ((float4*)avp)[(r * 4 + kq) * 32 + c4] = acc;
    }
    __syncthreads();
    if (tid < 128) {
        const int r = tid >> 5, c4 = tid & 31;
        float4 s0 = ((const float4*)avp)[(r * 4 + 0) * 32 + c4];
        const float4 s1 = ((const float4*)avp)[(r * 4 + 1) * 32 + c4];
        const float4 s2 = ((const float4*)avp)[(r * 4 + 2) * 32 + c4];
        const float4 s3 = ((const float4*)avp)[(r * 4 + 3) * 32 + c4];
        s0.x += s1.x + s2.x + s3.x; s0.y += s1.y + s2.y + s3.y;
        s0.z += s1.z + s2.z + s3.z; s0.w += s1.w + s2.w + s3.w;
        ((float4*)aoS)[r * 32 + c4] = s0;
    }
    __syncthreads();

    // ---- outproj, k-split x4 ----
    {
        const int kq = tid >> 7, unit = tid & 127, r = unit >> 5, c4 = unit & 31;
        const float4* W4 = (const float4*)Wd;
        const float* ap = aoS + r * 128 + kq * 32;
        float4 acc = make_float4(0.f, 0.f, 0.f, 0.f);
        #pragma unroll 8
        for (int k = 0; k < 32; ++k) {
            const float a = ap[k];
            const float4 w = W4[(kq * 32 + k) * 32 + c4];
            acc.x = fmaf(a, w.x, acc.x); acc.y = fmaf(a, w.y, acc.y);
            acc.z = fmaf(a, w.z, acc.z); acc.w = fmaf(a, w.w, acc.w);
        }
        ((float4*)pp)[kq * 128 + unit] = acc;
    }
    __syncthreads();

    // ---- combine + bias + residual + LN -> rowS (and out1 if SYM) ----
    if (tid < 128) {
        const int r = tid >> 5, c4 = tid & 31;
        const float4 p0 = ((const float4*)pp)[tid];
        const float4 p1 = ((const float4*)pp)[128 + tid];
        const float4 p2 = ((const float4*)pp)[256 + tid];
        const float4 p3 = ((const float4*)pp)[384 + tid];
        const float4 bv0 = ((const float4*)bd)[c4];
        const float4 r4 = ((const float4*)(res + (size_t)(r0 + r) * 128))[c4];
        const float x0 = p0.x + p1.x + p2.x + p3.x + bv0.x + r4.x;
        const float x1 = p0.y + p1.y + p2.y + p3.y + bv0.y + r4.y;
        const float x2 = p0.z + p1.z + p2.z + p3.z + bv0.z + r4.z;
        const float x3 = p0.w + p1.w + p2.w + p3.w + bv0.w + r4.w;
        float s  = x0 + x1 + x2 + x3;
        float s2 = x0 * x0 + x1 * x1 + x2 * x2 + x3 * x3;
        for (int o = 16; o; o >>= 1) { s += __shfl_xor(s, o, 32); s2 += __shfl_xor(s2, o, 32); }
        const float m = s * (1.f / 128), var = s2 * (1.f / 128) - m * m;
        const float rs = rsqrtf(var + LN_EPS);
        const float4 gv = ((const float4*)lg)[c4], bv = ((const float4*)lb)[c4];
        float4 o4;
        o4.x = (x0 - m) * rs * gv.x + bv.x; o4.y = (x1 - m) * rs * gv.y + bv.y;
        o4.z = (x2 - m) * rs * gv.z + bv.z; o4.w = (x3 - m) * rs * gv.w + bv.w;
        ((float4*)rowS)[r * 32 + c4] = o4;
        if (SYM) ((float4*)p.out1)[(size_t)(r0 + r) * 32 + c4] = o4;
    }
    __syncthreads();

    if (QPROJ) {
        float* qpp  = smem + 512;   // [4][4][32] f4 partials (2048 floats)
        float* q2wS = smem + 2560;  // [4][128]
        float* qp2  = smem + 1536;  // [2][2][128] f4 partials (2048 floats)
        {   // q2w partials, k-split x4
            const int kq = tid >> 7, unit = tid & 127, r = unit >> 5, c4 = unit & 31;
            const float4* W4 = (const float4*)p.Ww2;
            const float* ap = rowS + r * 128 + kq * 32;
            float4 acc = make_float4(0.f, 0.f, 0.f, 0.f);
            #pragma unroll 8
            for (int k = 0; k < 32; ++k) {
                const float a = ap[k];
                const float4 w = W4[(kq * 32 + k) * 32 + c4];
                acc.x = fmaf(a, w.x, acc.x); acc.y = fmaf(a, w.y, acc.y);
                acc.z = fmaf(a, w.z, acc.z); acc.w = fmaf(a, w.w, acc.w);
            }
            ((float4*)qpp)[kq * 128 + unit] = acc;
        }
        __syncthreads();
        if (tid < 128) {
            const int c4 = tid & 31;
            const float4 p0 = ((const float4*)qpp)[tid];
            const float4 p1 = ((const float4*)qpp)[128 + tid];
            const float4 p2 = ((const float4*)qpp)[256 + tid];
            const float4 p3 = ((const float4*)qpp)[384 + tid];
            const float4 bw = ((const float4*)p.bw2)[c4];
            ((float4*)q2wS)[tid] = make_float4(p0.x + p1.x + p2.x + p3.x + bw.x,
                                               p0.y + p1.y + p2.y + p3.y + bw.y,
                                               p0.z + p1.z + p2.z + p3.z + bw.z,
                                               p0.w + p1.w + p2.w + p3.w + bw.w);
        }
        __syncthreads();
        {   // qa2 = q2w@W1q + b1 ; qb2 = q2w@W1k + b1 ; k-split x2
            const int which = tid >> 8, sub = tid & 255;
            const int kh = sub >> 7, unit2 = sub & 127;
            const float4* W4 = (const float4*)(which ? p.W1k : p.W1q);
            const int r = unit2 >> 5, c4 = unit2 & 31;
            const float* ap = q2wS + r * 128 + kh * 64;
            float4 acc = make_float4(0.f, 0.f, 0.f, 0.f);
            #pragma unroll 8
            for (int k = 0; k < 64; ++k) {
                const float a = ap[k];
                const float4 w = W4[(kh * 64 + k) * 32 + c4];
                acc.x = fmaf(a, w.x, acc.x); acc.y = fmaf(a, w.y, acc.y);
                acc.z = fmaf(a, w.z, acc.z); acc.w = fmaf(a, w.w, acc.w);
            }
            ((float4*)qp2)[(which * 2 + kh) * 128 + unit2] = acc;
        }
        __syncthreads();
        if (tid < 256) {   // reduce 2 k-halves + b1 -> global
            const int which = tid >> 7, unit2 = tid & 127;
            const int r = unit2 >> 5, c4 = unit2 & 31;
            const float4 p0 = ((const float4*)qp2)[(which * 2 + 0) * 128 + unit2];
            const float4 p1 = ((const float4*)qp2)[(which * 2 + 1) * 128 + unit2];
            const float4 b1v = ((const float4*)p.b1)[c4];
            float* oq = which ? p.qb2 : p.qa2;
            ((float4*)oq)[(size_t)(r0 + r) * 32 + c4] =
                make_float4(p0.x + p1.x + b1v.x, p0.y + p1.y + b1v.y,
                            p0.z + p1.z + b1v.z, p0.w + p1.w + b1v.w);
        }
    }

    if (FFN) {
        float* hidP = smem + 512;   // [4 kh][4 r][512] partials; [0,2048) -> hidden
        float* part = smem + 8704;  // [16 kg][4 r][128]
        {   // ffn1: float4-col c of 128 (DFF/4), k-quarter kh; 4-row reg accs
            const int c = tid & 127, kh = tid >> 7;
            const float4* Wf1_4 = (const float4*)p.Wf1;
            float4 a0 = make_float4(0.f,0.f,0.f,0.f), a1 = a0, a2 = a0, a3 = a0;
            const int kbase = kh * 32;
            #pragma unroll 8
            for (int k = 0; k < 32; ++k) {
                const int kk = kbase + k;
                const float4 w = Wf1_4[kk * 128 + c];
                const float s0 = rowS[kk],       s1 = rowS[128 + kk];
                const float s2 = rowS[256 + kk], s3 = rowS[384 + kk];
                a0.x=fmaf(s0,w.x,a0.x); a0.y=fmaf(s0,w.y,a0.y); a0.z=fmaf(s0,w.z,a0.z); a0.w=fmaf(s0,w.w,a0.w);
                a1.x=fmaf(s1,w.x,a1.x); a1.y=fmaf(s1,w.y,a1.y); a1.z=fmaf(s1,w.z,a1.z); a1.w=fmaf(s1,w.w,a1.w);
                a2.x=fmaf(s2,w.x,a2.x); a2.y=fmaf(s2,w.y,a2.y); a2.z=fmaf(s2,w.z,a2.z); a2.w=fmaf(s2,w.w,a2.w);
                a3.x=fmaf(s3,w.x,a3.x); a3.y=fmaf(s3,w.y,a3.y); a3.z=fmaf(s3,w.z,a3.z); a3.w=fmaf(s3,w.w,a3.w);
            }
            float4* h4 = (float4*)hidP;
            const int base = kh * 512;
            h4[base + 0*128 + c] = a0; h4[base + 1*128 + c] = a1;
            h4[base + 2*128 + c] = a2; h4[base + 3*128 + c] = a3;
        }
        __syncthreads();
        for (int i = tid; i < 2048; i += 512) {   // reduce 4 k-quarters + relu
            hidP[i] = fmaxf(hidP[i] + hidP[2048 + i] + hidP[4096 + i] + hidP[6144 + i]
                            + p.bf1[i & 511], 0.f);
        }
        __syncthreads();
        {   // ffn2: c4f of 32, k-group kg (16 x 32); 4-row reg accs
            const int c4f = tid & 31, kg = tid >> 5;
            const float4* Wf2_4 = (const float4*)p.Wf2;
            float4 a0 = make_float4(0.f,0.f,0.f,0.f), a1 = a0, a2 = a0, a3 = a0;
            const int kbase = kg * 32;
            const float* h0 = hidP + 0 * 512 + kbase;
            const float* h1 = hidP + 1 * 512 + kbase;
            const float* h2 = hidP + 2 * 512 + kbase;
            const float* h3 = hidP + 3 * 512 + kbase;
            #pragma unroll 8
            for (int k = 0; k < 32; ++k) {
                const float4 w = Wf2_4[(kbase + k) * 32 + c4f];
                const float s0 = h0[k], s1 = h1[k], s2 = h2[k], s3 = h3[k];
                a0.x=fmaf(s0,w.x,a0.x); a0.y=fmaf(s0,w.y,a0.y); a0.z=fmaf(s0,w.z,a0.z); a0.w=fmaf(s0,w.w,a0.w);
                a1.x=fmaf(s1,w.x,a1.x); a1.y=fmaf(s1,w.y,a1.y); a1.z=fmaf(s1,w.z,a1.z); a1.w=fmaf(s1,w.w,a1.w);
                a2.x=fmaf(s2,w.x,a2.x); a2.y=fmaf(s2,w.y,a2.y); a2.z=fmaf(s2,w.z,a2.z); a2.w=fmaf(s2,w.w,a2.w);
                a3.x=fmaf(s3,w.x,a3.x); a3.y=fmaf(s3,w.y,a3.y); a3.z=fmaf(s3,w.z,a3.z); a3.w=fmaf(s3,w.w,a3.w);
            }
            float4* p4 = (float4*)part;
            p4[kg * 128 + 0 * 32 + c4f] = a0; p4[kg * 128 + 1 * 32 + c4f] = a1;
            p4[kg * 128 + 2 * 32 + c4f] = a2; p4[kg * 128 + 3 * 32 + c4f] = a3;
        }
        __syncthreads();
        if (tid < 128) {  // reduce 16 k-partials + bias + residual + LN3 -> out
            const int r = tid >> 5, c4 = tid & 31;
            const float4* p4 = (const float4*)part;
            float4 sum = ((const float4*)p.bf2)[c4];
            #pragma unroll
            for (int kg = 0; kg < 16; ++kg) {
                const float4 v = p4[kg * 128 + r * 32 + c4];
                sum.x += v.x; sum.y += v.y; sum.z += v.z; sum.w += v.w;
            }
            const float4 r4 = ((const float4*)rowS)[r * 32 + c4];
            const float x0 = sum.x + r4.x, x1 = sum.y + r4.y;
            const float x2 = sum.z + r4.z, x3 = sum.w + r4.w;
            float s  = x0 + x1 + x2 + x3;
            float s2 = x0 * x0 + x1 * x1 + x2 * x2 + x3 * x3;
            for (int o = 16; o; o >>= 1) { s += __shfl_xor(s, o, 32); s2 += __shfl_xor(s2, o, 32); }
            const float m = s * (1.f / 128), var = s2 * (1.f / 128) - m * m;
            const float rs = rsqrtf(var + LN_EPS);
            const float4 gv = ((const float4*)p.ln3g)[c4], bv = ((const float4*)p.ln3b)[c4];
            float4 o4;
            o4.x = (x0 - m) * rs * gv.x + bv.x; o4.y = (x1 - m) * rs * gv.y + bv.y;
            o4.z = (x2 - m) * rs * gv.z + bv.z; o4.w = (x3 - m) * rs * gv.w + bv.w;
            ((float4*)p.out)[(size_t)(r0 + r) * 32 + c4] = o4;
        }
    }
}

extern "C" void kernel_launch(void* const* d_in, const int* in_sizes, int n_in,
                              void* d_out, int out_size, void* d_ws, size_t ws_size,
                              hipStream_t stream) {
    (void)in_sizes; (void)n_in; (void)out_size; (void)ws_size;
    P p;
    p.x        = (const float*)d_in[0];
    p.enc      = (const float*)d_in[1];
    p.com_mask = (const float*)d_in[2];
    p.dec_mask = (const float*)d_in[3];
    p.W1q = (const float*)d_in[4];
    p.W1k = (const float*)d_in[5];
    p.b1  = (const float*)d_in[6];
    p.W2  = (const float*)d_in[7];
    // d_in[8] = b2: per-row constant -> dropped (softmax shift invariance)
    p.Ww1 = (const float*)d_in[9];
    p.bw1 = (const float*)d_in[10];
    p.Wd1 = (const float*)d_in[11];
    p.bd1 = (const float*)d_in[12];
    p.Ww2 = (const float*)d_in[13];
    p.bw2 = (const float*)d_in[14];
    p.Wd2 = (const float*)d_in[15];
    p.bd2 = (const float*)d_in[16];
    p.Wf1 = (const float*)d_in[17];
    p.bf1 = (const float*)d_in[18];
    p.Wf2 = (const float*)d_in[19];
    p.bf2 = (const float*)d_in[20];
    p.ln1g = (const float*)d_in[21];
    p.ln1b = (const float*)d_in[22];
    p.ln2g = (const float*)d_in[23];
    p.ln2b = (const float*)d_in[24];
    p.ln3g = (const float*)d_in[25];
    p.ln3b = (const float*)d_in[26];
    p.out  = (float*)d_out;

    float* ws = (float*)d_ws;
    const size_t RD  = (size_t)R * D;      // 131072
    const size_t SSz = (size_t)B * S * S;  // 262144
    p.xw    = ws;
    p.qa    = p.xw    + RD;
    p.kb    = p.qa    + RD;
    p.kv2w  = p.kb    + RD;
    p.kb2   = p.kv2w  + RD;
    p.ka2   = p.kb2   + RD;
    p.qa2   = p.ka2   + RD;
    p.qb2   = p.qa2   + RD;
    p.sbuf  = p.qb2   + RD;    // SSz
    p.sbuf2 = p.sbuf  + SSz;   // SSz
    p.out1  = p.sbuf2 + SSz;

    proj3_kernel<<<dim3(R / 8, 2), 512, 0, stream>>>(p);
    pairwise_self_kernel<<<dim3(8, 8, 4), 512, 0, stream>>>(p);
    attn_tail_kernel<true, true, false><<<R / 4, 512, 0, stream>>>(p);
    pairwise_cross2_kernel<<<dim3(8, 8, 4), 512, 0, stream>>>(p);
    attn_tail_kernel<false, false, true><<<R / 4, 512, 0, stream>>>(p);
}